// Round 4
// baseline (512.936 us; speedup 1.0000x reference)
//
#include <hip/hip_runtime.h>
#include <cmath>

namespace {

typedef _Float16 half8 __attribute__((ext_vector_type(8)));
typedef float f32x4 __attribute__((ext_vector_type(4)));

constexpr int kTokens = 16384;
constexpr int kD      = 7168;
constexpr int kE      = 256;
constexpr int kTopK   = 8;
constexpr float kRouteScale = 2.5f;

constexpr int BM = 64;
constexpr int BK = 32;
constexpr int NT = kD / BK;              // 224 k-tiles
constexpr float kS  = 4096.0f;           // limb scale 2^12
constexpr float kC  = 0.000244140625f;   // 2^-12 (exact)
constexpr size_t kWsTileB = 32768;       // per-ktile W image: limb0 16K + limb1 16K
constexpr size_t kWsNeed  = (size_t)NT * kWsTileB;   // 7,340,032 B

// ---------------------------------------------------------------------------
// Pre-pass: W [256][7168] f32 -> per-ktile B-fragment images, 2 scaled f16
// limbs.  Slot for expert e, k-group kg (8 k's): (e>>4)*64 + kg*16 + (e&15).
// Lane l of a wave reading slot base + l*16 gets exactly its MFMA B fragment.
// ---------------------------------------------------------------------------
__global__ void wconv_kernel(const float* __restrict__ W, unsigned char* __restrict__ ws)
{
    const int e = blockIdx.x;
    const int t = threadIdx.x;            // 0..895
    const float* src = W + (size_t)e * kD + (size_t)t * 8;
    float v[8];
    *reinterpret_cast<float4*>(v)     = *reinterpret_cast<const float4*>(src);
    *reinterpret_cast<float4*>(v + 4) = *reinterpret_cast<const float4*>(src + 4);
    half8 h, l;
#pragma unroll
    for (int j = 0; j < 8; ++j) {
        _Float16 hh = (_Float16)v[j];
        h[j] = hh;
        l[j] = (_Float16)((v[j] - (float)hh) * kS);
    }
    const int kt = t >> 2;
    const int kg = t & 3;
    const size_t off = (size_t)kt * kWsTileB +
                       (size_t)(((e >> 4) << 6) + (kg << 4) + (e & 15)) * 16;
    *reinterpret_cast<half8*>(ws + off)         = h;
    *reinterpret_cast<half8*>(ws + off + 16384) = l;
}

// ---------------------------------------------------------------------------
// Main fused kernel: barrier-free MFMA main loop, no LDS staging.
// 512 threads = 8 waves; block tile 64x256; wave tile 64x32 (4 row-frags x
// 2 col-frags).  A loaded per-lane direct from x (L1-broadcast across the 8
// waves) and split into 2 f16 limbs in registers; B loaded per-lane direct
// from the pre-baked fragment images (L2/L3-resident).  3 MFMA products per
// frag-pair (xh*wh -> acc0; xm*wh + xh*wl -> acc1); acc0 Kahan-spilled every
// 16 tiles.  LDS used only by the epilogue score buffer.
// ---------------------------------------------------------------------------
__global__ __launch_bounds__(512, 2)
void gate_mfma(const float* __restrict__ x,
               const unsigned char* __restrict__ wst,
               const float* __restrict__ bias,
               float* __restrict__ out)
{
    __shared__ float sc[64][257];        // 65792 B, epilogue only

    const int t    = threadIdx.x;
    const int lane = t & 63;
    const int wid  = t >> 6;             // 0..7 -> 32-col group
    const int m0   = blockIdx.x * BM;
    const int l15  = lane & 15;
    const int lg   = lane >> 4;

    // A: lane holds A[row = i*16 + l15][k = kt*32 + lg*8 + e]
    const float* xb = x + (size_t)(m0 + l15) * kD + (size_t)(lg * 8);
    // B: lane l fragment = image + kt*32768 + (wid*2+j)*1024 + limb*16384 + l*16
    const unsigned char* bb = wst + (size_t)(wid * 2) * 1024 + (size_t)lane * 16;

    f32x4 acc0[4][2], acc1[4][2], accL[4][2], cmpL[4][2];
#pragma unroll
    for (int i = 0; i < 4; ++i)
#pragma unroll
        for (int j = 0; j < 2; ++j) {
            acc0[i][j] = f32x4{0.f,0.f,0.f,0.f};
            acc1[i][j] = f32x4{0.f,0.f,0.f,0.f};
            accL[i][j] = f32x4{0.f,0.f,0.f,0.f};
            cmpL[i][j] = f32x4{0.f,0.f,0.f,0.f};
        }

    float xA[4][8], xB[4][8];
    half8 bA[2][2], bB[2][2];

    auto LOADX = [&](float (&xr)[4][8], int kt) {
        const float* p = xb + kt * BK;
#pragma unroll
        for (int i = 0; i < 4; ++i) {
            *reinterpret_cast<float4*>(&xr[i][0]) =
                *reinterpret_cast<const float4*>(p + (size_t)i * (16 * kD));
            *reinterpret_cast<float4*>(&xr[i][4]) =
                *reinterpret_cast<const float4*>(p + (size_t)i * (16 * kD) + 4);
        }
    };
    auto LOADB = [&](half8 (&br)[2][2], int kt) {
        const unsigned char* p = bb + (size_t)kt * kWsTileB;
#pragma unroll
        for (int j = 0; j < 2; ++j) {
            br[j][0] = *reinterpret_cast<const half8*>(p + j * 1024);
            br[j][1] = *reinterpret_cast<const half8*>(p + j * 1024 + 16384);
        }
    };
    auto COMPUTE = [&](float (&xr)[4][8], half8 (&br)[2][2]) {
        half8 ah[4], am[4];
#pragma unroll
        for (int i = 0; i < 4; ++i) {
#pragma unroll
            for (int e = 0; e < 8; ++e) {
                const float v = xr[i][e];
                const _Float16 a = (_Float16)v;
                const float r1 = v - (float)a;
                ah[i][e] = a;
                am[i][e] = (_Float16)(r1 * kS);
            }
        }
        // product-major order: max dependency distance on acc1 chains
#pragma unroll
        for (int i = 0; i < 4; ++i)
#pragma unroll
            for (int j = 0; j < 2; ++j)
                acc0[i][j] = __builtin_amdgcn_mfma_f32_16x16x32_f16(ah[i], br[j][0], acc0[i][j], 0, 0, 0);
#pragma unroll
        for (int i = 0; i < 4; ++i)
#pragma unroll
            for (int j = 0; j < 2; ++j)
                acc1[i][j] = __builtin_amdgcn_mfma_f32_16x16x32_f16(am[i], br[j][0], acc1[i][j], 0, 0, 0);
#pragma unroll
        for (int i = 0; i < 4; ++i)
#pragma unroll
            for (int j = 0; j < 2; ++j)
                acc1[i][j] = __builtin_amdgcn_mfma_f32_16x16x32_f16(ah[i], br[j][1], acc1[i][j], 0, 0, 0);
    };

    // prologue
    LOADX(xA, 0); LOADB(bA, 0);

    for (int kt = 0; kt < NT; kt += 2) {
        LOADX(xB, kt + 1); LOADB(bB, kt + 1);     // kt+1 <= 223 always valid
        COMPUTE(xA, bA);
        if (kt + 2 < NT) { LOADX(xA, kt + 2); LOADB(bA, kt + 2); }
        COMPUTE(xB, bB);
        if (((kt + 2) & 15) == 0) {               // Kahan spill of acc0 (uniform branch)
#pragma unroll
            for (int i = 0; i < 4; ++i)
#pragma unroll
                for (int j = 0; j < 2; ++j) {
                    f32x4 y = acc0[i][j] - cmpL[i][j];
                    f32x4 s = accL[i][j] + y;
                    cmpL[i][j] = (s - accL[i][j]) - y;
                    accL[i][j] = s;
                    acc0[i][j] = f32x4{0.f,0.f,0.f,0.f};
                }
        }
    }

    // ---- epilogue: combine limb levels, biased scores -> LDS
#pragma unroll
    for (int j = 0; j < 2; ++j) {
        const int col  = wid * 32 + j * 16 + l15;
        const float bv = bias[col];
#pragma unroll
        for (int i = 0; i < 4; ++i) {
            f32x4 z = accL[i][j] + kC * acc1[i][j];
#pragma unroll
            for (int r = 0; r < 4; ++r) {
                const int row = i * 16 + lg * 4 + r;
                const float s = 1.0f / (1.0f + expf(-z[r]));
                sc[row][col] = s + bv;
            }
        }
    }
    __syncthreads();

    // ---- top-8 per row: 8 lanes/row, iterative argmax, ties -> lowest index
    const int rr = t >> 3;
    const int g  = t & 7;

    float cval[kTopK];
    int   cidx[kTopK];

#pragma unroll
    for (int r = 0; r < kTopK; ++r) {
        float best = -INFINITY;
        int   bi   = kE;
        const float* rowp = sc[rr] + g * 32;
#pragma unroll 8
        for (int c = 0; c < 32; ++c) {
            const float v  = rowp[c];
            const int   ci = g * 32 + c;
            if (v > best || (v == best && ci < bi)) { best = v; bi = ci; }
        }
#pragma unroll
        for (int off = 4; off > 0; off >>= 1) {
            const float ov = __shfl_xor(best, off, 8);
            const int   oi = __shfl_xor(bi,   off, 8);
            if (ov > best || (ov == best && oi < bi)) { best = ov; bi = oi; }
        }
        cval[r] = best;
        cidx[r] = bi;
        if ((bi >> 5) == g) sc[rr][bi] = -INFINITY;   // owner lane retires winner
        __syncthreads();
    }

    if (g == 0) {
        float uw[kTopK];
        float wsum = 0.0f;
#pragma unroll
        for (int r = 0; r < kTopK; ++r) {
            uw[r] = cval[r] - bias[cidx[r]];   // recover unbiased sigmoid score
            wsum += uw[r];
        }
        const float scale = kRouteScale / wsum;
        const size_t grow = (size_t)(m0 + rr);
#pragma unroll
        for (int r = 0; r < kTopK; ++r)
            out[grow * kTopK + r] = uw[r] * scale;
#pragma unroll
        for (int r = 0; r < kTopK; ++r)
            out[(size_t)kTokens * kTopK + grow * kTopK + r] = (float)cidx[r];
    }
}

// ---------------------------------------------------------------------------
// Fallback (round-1 fp32 kernel, known-good) if ws is too small.
// ---------------------------------------------------------------------------
constexpr int FBM = 32;
constexpr int FBK = 32;
constexpr int XS_STRIDE = 36;
constexpr int SC_STRIDE = 260;

__global__ __launch_bounds__(256, 2)
void gate_fused(const float* __restrict__ x,
                const float* __restrict__ W,
                const float* __restrict__ bias,
                float* __restrict__ out)
{
    __shared__ float smem[FBK * XS_STRIDE + FBK * kE];
    float (*xs)[XS_STRIDE] = reinterpret_cast<float (*)[XS_STRIDE]>(smem);
    float (*ws)[kE]        = reinterpret_cast<float (*)[kE]>(smem + FBK * XS_STRIDE);
    float (*sc)[SC_STRIDE] = reinterpret_cast<float (*)[SC_STRIDE]>(smem);

    const int t  = threadIdx.x;
    const int tx = t & 31;
    const int ty = t >> 5;
    const int m0 = blockIdx.x * FBM;
    const int lm = t >> 3;
    const int lc = t & 7;

    float acc[4][8];
    float cmp[4][8];
#pragma unroll
    for (int i = 0; i < 4; ++i)
#pragma unroll
        for (int j = 0; j < 8; ++j) { acc[i][j] = 0.0f; cmp[i][j] = 0.0f; }

    const float* xrow = x + (size_t)(m0 + lm) * kD;
    const float* wrow = W + (size_t)t * kD;

    for (int k0 = 0; k0 < kD; k0 += FBK) {
        float4 xv = *reinterpret_cast<const float4*>(xrow + k0 + 4 * lc);
        float4 wv[8];
#pragma unroll
        for (int i = 0; i < 8; ++i)
            wv[i] = *reinterpret_cast<const float4*>(wrow + k0 + 4 * i);
        __syncthreads();
        xs[4 * lc + 0][lm] = xv.x; xs[4 * lc + 1][lm] = xv.y;
        xs[4 * lc + 2][lm] = xv.z; xs[4 * lc + 3][lm] = xv.w;
#pragma unroll
        for (int i = 0; i < 8; ++i) {
            ws[4 * i + 0][t] = wv[i].x; ws[4 * i + 1][t] = wv[i].y;
            ws[4 * i + 2][t] = wv[i].z; ws[4 * i + 3][t] = wv[i].w;
        }
        __syncthreads();
        float p[4][8];
#pragma unroll
        for (int i = 0; i < 4; ++i)
#pragma unroll
            for (int j = 0; j < 8; ++j) p[i][j] = 0.0f;
#pragma unroll
        for (int k = 0; k < FBK; ++k) {
            float a[4], b[8];
            *reinterpret_cast<float4*>(a)     = *reinterpret_cast<const float4*>(&xs[k][4 * ty]);
            *reinterpret_cast<float4*>(b)     = *reinterpret_cast<const float4*>(&ws[k][4 * tx]);
            *reinterpret_cast<float4*>(b + 4) = *reinterpret_cast<const float4*>(&ws[k][128 + 4 * tx]);
#pragma unroll
            for (int i = 0; i < 4; ++i)
#pragma unroll
                for (int j = 0; j < 8; ++j)
                    p[i][j] = fmaf(a[i], b[j], p[i][j]);
        }
#pragma unroll
        for (int i = 0; i < 4; ++i)
#pragma unroll
            for (int j = 0; j < 8; ++j) {
                const float y = p[i][j] - cmp[i][j];
                const float s = acc[i][j] + y;
                cmp[i][j] = (s - acc[i][j]) - y;
                acc[i][j] = s;
            }
    }
    __syncthreads();
#pragma unroll
    for (int i = 0; i < 4; ++i) {
        const int row = 4 * ty + i;
#pragma unroll
        for (int j = 0; j < 8; ++j) {
            const int col = (j < 4) ? (4 * tx + j) : (128 + 4 * tx + (j - 4));
            const float s = 1.0f / (1.0f + expf(-acc[i][j]));
            sc[row][col] = s + bias[col];
        }
    }
    __syncthreads();
    const int rr = t >> 3;
    const int g  = t & 7;
    float cval[kTopK];
    int   cidx[kTopK];
#pragma unroll
    for (int r = 0; r < kTopK; ++r) {
        float best = -INFINITY;
        int   bi   = kE;
        const float* rowp = sc[rr] + g * 32;
#pragma unroll 8
        for (int c = 0; c < 32; ++c) {
            const float v  = rowp[c];
            const int   ci = g * 32 + c;
            if (v > best || (v == best && ci < bi)) { best = v; bi = ci; }
        }
#pragma unroll
        for (int off = 4; off > 0; off >>= 1) {
            const float ov = __shfl_xor(best, off, 8);
            const int   oi = __shfl_xor(bi,   off, 8);
            if (ov > best || (ov == best && oi < bi)) { best = ov; bi = oi; }
        }
        cval[r] = best; cidx[r] = bi;
        if ((bi >> 5) == g) sc[rr][bi] = -INFINITY;
        __syncthreads();
    }
    if (g == 0) {
        float uw[kTopK];
        float wsum = 0.0f;
#pragma unroll
        for (int r = 0; r < kTopK; ++r) { uw[r] = cval[r] - bias[cidx[r]]; wsum += uw[r]; }
        const float scale = kRouteScale / wsum;
        const size_t grow = (size_t)(m0 + rr);
#pragma unroll
        for (int r = 0; r < kTopK; ++r) out[grow * kTopK + r] = uw[r] * scale;
#pragma unroll
        for (int r = 0; r < kTopK; ++r)
            out[(size_t)kTokens * kTopK + grow * kTopK + r] = (float)cidx[r];
    }
}

} // namespace

extern "C" void kernel_launch(void* const* d_in, const int* in_sizes, int n_in,
                              void* d_out, int out_size, void* d_ws, size_t ws_size,
                              hipStream_t stream)
{
    const float* x    = (const float*)d_in[0];
    const float* W    = (const float*)d_in[1];
    const float* bias = (const float*)d_in[2];
    float* out = (float*)d_out;

    if (ws_size >= kWsNeed) {
        unsigned char* ws = (unsigned char*)d_ws;
        hipLaunchKernelGGL(wconv_kernel, dim3(kE), dim3(kD / 8), 0, stream, W, ws);
        hipLaunchKernelGGL(gate_mfma, dim3(kTokens / BM), dim3(512), 0, stream, x, ws, bias, out);
    } else {
        hipLaunchKernelGGL(gate_fused, dim3(kTokens / FBM), dim3(256), 0, stream, x, W, bias, out);
    }
}

// Round 5
// 306.747 us; speedup vs baseline: 1.6722x; 1.6722x over previous
//
#include <hip/hip_runtime.h>
#include <cmath>

namespace {

typedef _Float16 half8 __attribute__((ext_vector_type(8)));
typedef float f32x4 __attribute__((ext_vector_type(4)));

constexpr int kTokens = 16384;
constexpr int kD      = 7168;
constexpr int kE      = 256;
constexpr int kTopK   = 8;
constexpr float kRouteScale = 2.5f;

constexpr int BM = 32;
constexpr int BK = 32;
constexpr int NT = kD / BK;              // 224 k-tiles
constexpr float kS  = 4096.0f;           // limb scale 2^12
constexpr float kC  = 0.000244140625f;   // 2^-12 (exact)
constexpr size_t kWsTileB = 32768;       // per-ktile W image: limb0 16K + limb1 16K
constexpr size_t kWsNeed  = (size_t)NT * kWsTileB;   // 7,340,032 B

// ---------------------------------------------------------------------------
// Pre-pass: W [256][7168] f32 -> per-ktile B-fragment images, 2 scaled f16
// limbs.  Slot for expert e, k-group kg (8 k's): (e>>4)*64 + kg*16 + (e&15).
// Lane l of a wave reading colfrag f at f*1024 + l*16 gets its MFMA B frag.
// ---------------------------------------------------------------------------
__global__ void wconv_kernel(const float* __restrict__ W, unsigned char* __restrict__ ws)
{
    const int e = blockIdx.x;
    const int t = threadIdx.x;            // 0..895
    const float* src = W + (size_t)e * kD + (size_t)t * 8;
    float v[8];
    *reinterpret_cast<float4*>(v)     = *reinterpret_cast<const float4*>(src);
    *reinterpret_cast<float4*>(v + 4) = *reinterpret_cast<const float4*>(src + 4);
    half8 h, l;
#pragma unroll
    for (int j = 0; j < 8; ++j) {
        _Float16 hh = (_Float16)v[j];
        h[j] = hh;
        l[j] = (_Float16)((v[j] - (float)hh) * kS);
    }
    const int kt = t >> 2;
    const int kg = t & 3;
    const size_t off = (size_t)kt * kWsTileB +
                       (size_t)(((e >> 4) << 6) + (kg << 4) + (e & 15)) * 16;
    *reinterpret_cast<half8*>(ws + off)         = h;
    *reinterpret_cast<half8*>(ws + off + 16384) = l;
}

// ---------------------------------------------------------------------------
// Main fused kernel.  512 threads = 8 waves; block tile 32x256; wave tile
// 32x32 (2 row-frags x 2 col-frags).  Barrier convoy per k-tile (locality!).
// A: staged through a small LDS double buffer as pre-converted f16 limbs
//    (8x reuse across waves).  B: direct global->reg ping-pong from the
//    pre-baked fragment images (zero intra-block reuse -> no LDS).
// 3 MFMA products per frag-pair: xh*wh -> acc0; xm*wh + xh*wl -> acc1.
// acc0 Kahan-spilled every 16 tiles.  Grid 512 = 2 blocks/CU.
// LDS: A bufs 2x4096 at [0,8192), aliased by epilogue sc[32][257] (32896 B).
// ---------------------------------------------------------------------------
__global__ __launch_bounds__(512, 4)
void gate_mfma(const float* __restrict__ x,
               const unsigned char* __restrict__ wst,
               const float* __restrict__ bias,
               float* __restrict__ out)
{
    __shared__ unsigned char lds[32896];

    const int t    = threadIdx.x;
    const int lane = t & 63;
    const int wid  = t >> 6;             // 0..7 -> 32-col group
    const int m0   = blockIdx.x * BM;
    const int l15  = lane & 15;
    const int lg   = lane >> 4;

    // --- A staging map: thread t stages 2 k's of one row.
    // r = t>>4 (0..31), c = t&15 (k = 2c, 2c+1).
    // LDS addr (within buffer): i*2048 + L*1024 + (c>>2)*256 + (r&15)*16 + (c&3)*4
    const int sr = t >> 4;
    const int sc_ = t & 15;
    const unsigned aw = (unsigned)(((sr >> 4) << 11) + ((sc_ >> 2) << 8) +
                                   ((sr & 15) << 4) + ((sc_ & 3) << 2));
    const float* xs_base = x + (size_t)(m0 + sr) * kD + (size_t)(sc_ * 2);

    // --- B: lane's fragment pointer (colfrags wid*2, wid*2+1)
    const unsigned char* bb = wst + (size_t)(wid * 2) * 1024 + (size_t)lane * 16;

    f32x4 acc0[2][2], acc1[2][2], accL[2][2], cmpL[2][2];
#pragma unroll
    for (int i = 0; i < 2; ++i)
#pragma unroll
        for (int j = 0; j < 2; ++j) {
            acc0[i][j] = f32x4{0.f,0.f,0.f,0.f};
            acc1[i][j] = f32x4{0.f,0.f,0.f,0.f};
            accL[i][j] = f32x4{0.f,0.f,0.f,0.f};
            cmpL[i][j] = f32x4{0.f,0.f,0.f,0.f};
        }

    half8 bA[2][2], bB[2][2];

    auto LOADB = [&](half8 (&br)[2][2], int kt) {
        const unsigned char* p = bb + (size_t)kt * kWsTileB;
#pragma unroll
        for (int j = 0; j < 2; ++j) {
            br[j][0] = *reinterpret_cast<const half8*>(p + j * 1024);
            br[j][1] = *reinterpret_cast<const half8*>(p + j * 1024 + 16384);
        }
    };
    // convert 2 floats -> packed limb words and write into buffer b
    auto WRITEA = [&](int b, float2 xv) {
        const _Float16 a0 = (_Float16)xv.x;
        const _Float16 a1 = (_Float16)xv.y;
        const float r0 = xv.x - (float)a0;
        const float r1 = xv.y - (float)a1;
        const _Float16 m0h = (_Float16)(r0 * kS);
        const _Float16 m1h = (_Float16)(r1 * kS);
        union { _Float16 h[2]; unsigned u; } ph, pm;
        ph.h[0] = a0;  ph.h[1] = a1;
        pm.h[0] = m0h; pm.h[1] = m1h;
        const unsigned base = (unsigned)(b * 4096) + aw;
        *reinterpret_cast<unsigned*>(&lds[base])        = ph.u;
        *reinterpret_cast<unsigned*>(&lds[base + 1024]) = pm.u;
    };
    auto COMPUTE = [&](int b, half8 (&br)[2][2]) {
        const unsigned ab = (unsigned)(b * 4096) + (unsigned)(lane * 16);
        half8 xh[2], xm[2];
#pragma unroll
        for (int i = 0; i < 2; ++i) {
            xh[i] = *reinterpret_cast<const half8*>(&lds[ab + i * 2048]);
            xm[i] = *reinterpret_cast<const half8*>(&lds[ab + i * 2048 + 1024]);
        }
#pragma unroll
        for (int i = 0; i < 2; ++i)
#pragma unroll
            for (int j = 0; j < 2; ++j)
                acc0[i][j] = __builtin_amdgcn_mfma_f32_16x16x32_f16(xh[i], br[j][0], acc0[i][j], 0, 0, 0);
#pragma unroll
        for (int i = 0; i < 2; ++i)
#pragma unroll
            for (int j = 0; j < 2; ++j)
                acc1[i][j] = __builtin_amdgcn_mfma_f32_16x16x32_f16(xm[i], br[j][0], acc1[i][j], 0, 0, 0);
#pragma unroll
        for (int i = 0; i < 2; ++i)
#pragma unroll
            for (int j = 0; j < 2; ++j)
                acc1[i][j] = __builtin_amdgcn_mfma_f32_16x16x32_f16(xh[i], br[j][1], acc1[i][j], 0, 0, 0);
    };

    // ---- prologue: stage tile 0 into buf0, B tile 0 into bA
    {
        float2 xv = *reinterpret_cast<const float2*>(xs_base);
        WRITEA(0, xv);
        LOADB(bA, 0);
    }
    __syncthreads();

    for (int kt = 0; kt < NT; kt += 2) {
        // ---- tile kt: compute from buf0/bA, stage kt+1 -> buf1/bB
        {
            float2 xv = *reinterpret_cast<const float2*>(xs_base + (kt + 1) * BK);
            LOADB(bB, kt + 1);
            COMPUTE(0, bA);
            WRITEA(1, xv);
        }
        __syncthreads();
        // ---- tile kt+1: compute from buf1/bB, stage kt+2 -> buf0/bA
        {
            const bool pre = (kt + 2 < NT);
            float2 xv{0.f, 0.f};
            if (pre) { xv = *reinterpret_cast<const float2*>(xs_base + (kt + 2) * BK); LOADB(bA, kt + 2); }
            COMPUTE(1, bB);
            if (pre) WRITEA(0, xv);
        }
        if (((kt + 2) & 15) == 0) {      // Kahan spill of acc0 (uniform branch)
#pragma unroll
            for (int i = 0; i < 2; ++i)
#pragma unroll
                for (int j = 0; j < 2; ++j) {
                    f32x4 y = acc0[i][j] - cmpL[i][j];
                    f32x4 s = accL[i][j] + y;
                    cmpL[i][j] = (s - accL[i][j]) - y;
                    accL[i][j] = s;
                    acc0[i][j] = f32x4{0.f,0.f,0.f,0.f};
                }
        }
        __syncthreads();
    }

    // ---- epilogue: combine limb levels, biased scores -> LDS
    float (*sc)[257] = reinterpret_cast<float (*)[257]>(lds);   // 32896 B, aliases A bufs
#pragma unroll
    for (int j = 0; j < 2; ++j) {
        const int col  = wid * 32 + j * 16 + l15;
        const float bv = bias[col];
#pragma unroll
        for (int i = 0; i < 2; ++i) {
            f32x4 z = (accL[i][j] + acc0[i][j]) + kC * acc1[i][j];
#pragma unroll
            for (int r = 0; r < 4; ++r) {
                const int row = i * 16 + lg * 4 + r;
                const float s = 1.0f / (1.0f + expf(-z[r]));
                sc[row][col] = s + bv;
            }
        }
    }
    __syncthreads();

    // ---- top-8 per row: 16 lanes/row, iterative argmax, ties -> lowest index
    const int rr = t >> 4;
    const int g  = t & 15;

    float cval[kTopK];
    int   cidx[kTopK];

#pragma unroll
    for (int r = 0; r < kTopK; ++r) {
        float best = -INFINITY;
        int   bi   = kE;
        const float* rowp = sc[rr] + g * 16;
#pragma unroll 8
        for (int c = 0; c < 16; ++c) {
            const float v  = rowp[c];
            const int   ci = g * 16 + c;
            if (v > best || (v == best && ci < bi)) { best = v; bi = ci; }
        }
#pragma unroll
        for (int off = 8; off > 0; off >>= 1) {
            const float ov = __shfl_xor(best, off, 16);
            const int   oi = __shfl_xor(bi,   off, 16);
            if (ov > best || (ov == best && oi < bi)) { best = ov; bi = oi; }
        }
        cval[r] = best;
        cidx[r] = bi;
        if ((bi >> 4) == g) sc[rr][bi] = -INFINITY;   // owner lane retires winner
        __syncthreads();
    }

    if (g == 0) {
        float uw[kTopK];
        float wsum = 0.0f;
#pragma unroll
        for (int r = 0; r < kTopK; ++r) {
            uw[r] = cval[r] - bias[cidx[r]];   // recover unbiased sigmoid score
            wsum += uw[r];
        }
        const float scale = kRouteScale / wsum;
        const size_t grow = (size_t)(m0 + rr);
#pragma unroll
        for (int r = 0; r < kTopK; ++r)
            out[grow * kTopK + r] = uw[r] * scale;
#pragma unroll
        for (int r = 0; r < kTopK; ++r)
            out[(size_t)kTokens * kTopK + grow * kTopK + r] = (float)cidx[r];
    }
}

// ---------------------------------------------------------------------------
// Fallback (round-1 fp32 kernel, known-good) if ws is too small.
// ---------------------------------------------------------------------------
constexpr int FBM = 32;
constexpr int FBK = 32;
constexpr int XS_STRIDE = 36;
constexpr int SC_STRIDE = 260;

__global__ __launch_bounds__(256, 2)
void gate_fused(const float* __restrict__ x,
                const float* __restrict__ W,
                const float* __restrict__ bias,
                float* __restrict__ out)
{
    __shared__ float smem[FBK * XS_STRIDE + FBK * kE];
    float (*xs)[XS_STRIDE] = reinterpret_cast<float (*)[XS_STRIDE]>(smem);
    float (*ws)[kE]        = reinterpret_cast<float (*)[kE]>(smem + FBK * XS_STRIDE);
    float (*sc)[SC_STRIDE] = reinterpret_cast<float (*)[SC_STRIDE]>(smem);

    const int t  = threadIdx.x;
    const int tx = t & 31;
    const int ty = t >> 5;
    const int m0 = blockIdx.x * FBM;
    const int lm = t >> 3;
    const int lc = t & 7;

    float acc[4][8];
    float cmp[4][8];
#pragma unroll
    for (int i = 0; i < 4; ++i)
#pragma unroll
        for (int j = 0; j < 8; ++j) { acc[i][j] = 0.0f; cmp[i][j] = 0.0f; }

    const float* xrow = x + (size_t)(m0 + lm) * kD;
    const float* wrow = W + (size_t)t * kD;

    for (int k0 = 0; k0 < kD; k0 += FBK) {
        float4 xv = *reinterpret_cast<const float4*>(xrow + k0 + 4 * lc);
        float4 wv[8];
#pragma unroll
        for (int i = 0; i < 8; ++i)
            wv[i] = *reinterpret_cast<const float4*>(wrow + k0 + 4 * i);
        __syncthreads();
        xs[4 * lc + 0][lm] = xv.x; xs[4 * lc + 1][lm] = xv.y;
        xs[4 * lc + 2][lm] = xv.z; xs[4 * lc + 3][lm] = xv.w;
#pragma unroll
        for (int i = 0; i < 8; ++i) {
            ws[4 * i + 0][t] = wv[i].x; ws[4 * i + 1][t] = wv[i].y;
            ws[4 * i + 2][t] = wv[i].z; ws[4 * i + 3][t] = wv[i].w;
        }
        __syncthreads();
        float p[4][8];
#pragma unroll
        for (int i = 0; i < 4; ++i)
#pragma unroll
            for (int j = 0; j < 8; ++j) p[i][j] = 0.0f;
#pragma unroll
        for (int k = 0; k < FBK; ++k) {
            float a[4], b[8];
            *reinterpret_cast<float4*>(a)     = *reinterpret_cast<const float4*>(&xs[k][4 * ty]);
            *reinterpret_cast<float4*>(b)     = *reinterpret_cast<const float4*>(&ws[k][4 * tx]);
            *reinterpret_cast<float4*>(b + 4) = *reinterpret_cast<const float4*>(&ws[k][128 + 4 * tx]);
#pragma unroll
            for (int i = 0; i < 4; ++i)
#pragma unroll
                for (int j = 0; j < 8; ++j)
                    p[i][j] = fmaf(a[i], b[j], p[i][j]);
        }
#pragma unroll
        for (int i = 0; i < 4; ++i)
#pragma unroll
            for (int j = 0; j < 8; ++j) {
                const float y = p[i][j] - cmp[i][j];
                const float s = acc[i][j] + y;
                cmp[i][j] = (s - acc[i][j]) - y;
                acc[i][j] = s;
            }
    }
    __syncthreads();
#pragma unroll
    for (int i = 0; i < 4; ++i) {
        const int row = 4 * ty + i;
#pragma unroll
        for (int j = 0; j < 8; ++j) {
            const int col = (j < 4) ? (4 * tx + j) : (128 + 4 * tx + (j - 4));
            const float s = 1.0f / (1.0f + expf(-acc[i][j]));
            sc[row][col] = s + bias[col];
        }
    }
    __syncthreads();
    const int rr = t >> 3;
    const int g  = t & 7;
    float cval[kTopK];
    int   cidx[kTopK];
#pragma unroll
    for (int r = 0; r < kTopK; ++r) {
        float best = -INFINITY;
        int   bi   = kE;
        const float* rowp = sc[rr] + g * 32;
#pragma unroll 8
        for (int c = 0; c < 32; ++c) {
            const float v  = rowp[c];
            const int   ci = g * 32 + c;
            if (v > best || (v == best && ci < bi)) { best = v; bi = ci; }
        }
#pragma unroll
        for (int off = 4; off > 0; off >>= 1) {
            const float ov = __shfl_xor(best, off, 8);
            const int   oi = __shfl_xor(bi,   off, 8);
            if (ov > best || (ov == best && oi < bi)) { best = ov; bi = oi; }
        }
        cval[r] = best; cidx[r] = bi;
        if ((bi >> 5) == g) sc[rr][bi] = -INFINITY;
        __syncthreads();
    }
    if (g == 0) {
        float uw[kTopK];
        float wsum = 0.0f;
#pragma unroll
        for (int r = 0; r < kTopK; ++r) { uw[r] = cval[r] - bias[cidx[r]]; wsum += uw[r]; }
        const float scale = kRouteScale / wsum;
        const size_t grow = (size_t)(m0 + rr);
#pragma unroll
        for (int r = 0; r < kTopK; ++r) out[grow * kTopK + r] = uw[r] * scale;
#pragma unroll
        for (int r = 0; r < kTopK; ++r)
            out[(size_t)kTokens * kTopK + grow * kTopK + r] = (float)cidx[r];
    }
}

} // namespace

extern "C" void kernel_launch(void* const* d_in, const int* in_sizes, int n_in,
                              void* d_out, int out_size, void* d_ws, size_t ws_size,
                              hipStream_t stream)
{
    const float* x    = (const float*)d_in[0];
    const float* W    = (const float*)d_in[1];
    const float* bias = (const float*)d_in[2];
    float* out = (float*)d_out;

    if (ws_size >= kWsNeed) {
        unsigned char* ws = (unsigned char*)d_ws;
        hipLaunchKernelGGL(wconv_kernel, dim3(kE), dim3(kD / 8), 0, stream, W, ws);
        hipLaunchKernelGGL(gate_mfma, dim3(kTokens / BM), dim3(512), 0, stream, x, ws, bias, out);
    } else {
        hipLaunchKernelGGL(gate_fused, dim3(kTokens / FBM), dim3(256), 0, stream, x, W, bias, out);
    }
}

// Round 6
// 259.664 us; speedup vs baseline: 1.9754x; 1.1813x over previous
//
#include <hip/hip_runtime.h>
#include <cmath>

namespace {

typedef _Float16 half8 __attribute__((ext_vector_type(8)));
typedef float f32x4 __attribute__((ext_vector_type(4)));

constexpr int kTokens = 16384;
constexpr int kD      = 7168;
constexpr int kE      = 256;
constexpr int kTopK   = 8;
constexpr float kRouteScale = 2.5f;

constexpr int BM     = 32;
constexpr int BK     = 32;               // MFMA k-tile
constexpr int KSTEP  = 128;              // k per barrier step (4 tiles)
constexpr int NT     = kD / BK;          // 224 k-tiles
constexpr int NSTEP  = kD / KSTEP;       // 56 steps
constexpr float kS  = 4096.0f;           // limb scale 2^12
constexpr float kC  = 0.000244140625f;   // 2^-12 (exact)
constexpr size_t kWsTileB = 32768;       // per-ktile W image: limb0 16K + limb1 16K
constexpr size_t kWsNeed  = (size_t)NT * kWsTileB;   // 7,340,032 B

// ---------------------------------------------------------------------------
// Pre-pass: W [256][7168] f32 -> per-ktile B-fragment images, 2 scaled f16
// limbs.  Slot for expert e, k-group kg (8 k's): (e>>4)*64 + kg*16 + (e&15).
// Lane l of a wave reading colfrag f at f*1024 + l*16 gets its MFMA B frag.
// ---------------------------------------------------------------------------
__global__ void wconv_kernel(const float* __restrict__ W, unsigned char* __restrict__ ws)
{
    const int e = blockIdx.x;
    const int t = threadIdx.x;            // 0..895
    const float* src = W + (size_t)e * kD + (size_t)t * 8;
    float v[8];
    *reinterpret_cast<float4*>(v)     = *reinterpret_cast<const float4*>(src);
    *reinterpret_cast<float4*>(v + 4) = *reinterpret_cast<const float4*>(src + 4);
    half8 h, l;
#pragma unroll
    for (int j = 0; j < 8; ++j) {
        _Float16 hh = (_Float16)v[j];
        h[j] = hh;
        l[j] = (_Float16)((v[j] - (float)hh) * kS);
    }
    const int kt = t >> 2;
    const int kg = t & 3;
    const size_t off = (size_t)kt * kWsTileB +
                       (size_t)(((e >> 4) << 6) + (kg << 4) + (e & 15)) * 16;
    *reinterpret_cast<half8*>(ws + off)         = h;
    *reinterpret_cast<half8*>(ws + off + 16384) = l;
}

// ---------------------------------------------------------------------------
// Main fused kernel.  512 threads = 8 waves; block tile 32x256; wave tile
// 32x32 (2 row-frags x 2 col-frags).  Barrier step = 128 k's (4 MFMA tiles):
// x prefetch distance = 4 tiles of compute (~1000cy) > HBM latency (~900cy),
// and barriers drop 224 -> 56.  A staged in LDS as pre-converted f16 limbs
// with XOR slot swizzle (conflict-free write AND read).  B direct global->reg
// ping-pong from pre-baked fragment images (no intra-block reuse -> no LDS).
// 3 MFMA products: xh*wh -> acc0; xm*wh + xh*wl -> acc1 (validated absmax 0).
// acc0 Kahan-spilled every 16 tiles.  Grid 512 = 2 blocks/CU.
// LDS: A bufs 2x16KB, aliased by epilogue sc[32][257] (32896 B total).
// A-buffer layout (16KB): ktile*4096 + limb*2048 + rowfrag*1024 + kg*256
//                         + ((row15 ^ (ktile*4+kg))&15)*16
// ---------------------------------------------------------------------------
__global__ __launch_bounds__(512, 4)
void gate_mfma(const float* __restrict__ x,
               const unsigned char* __restrict__ wst,
               const float* __restrict__ bias,
               float* __restrict__ out)
{
    __shared__ unsigned char lds[32896];

    const int t    = threadIdx.x;
    const int lane = t & 63;
    const int wid  = t >> 6;             // 0..7 -> 32-col group
    const int m0   = blockIdx.x * BM;
    const int l15  = lane & 15;
    const int lg   = lane >> 4;

    // --- A staging map: thread t stages 8 consecutive k's of one row.
    const int srow = t >> 4;             // 0..31
    const int skc  = t & 15;             // k chunk: k = skc*8 .. +7 (within step)
    const unsigned waddr = (unsigned)(((skc >> 2) << 12) + ((srow >> 4) << 10) +
                                      ((skc & 3) << 8) + ((((srow & 15) ^ skc) & 15) << 4));
    const float* xsrc = x + (size_t)(m0 + srow) * kD + (size_t)(skc * 8);

    // --- A fragment read offsets per ktile kk (limb0, rowfrag0 base)
    unsigned roff[4];
#pragma unroll
    for (int kk = 0; kk < 4; ++kk)
        roff[kk] = (unsigned)((kk << 12) + (lg << 8) +
                              (((l15 ^ ((kk << 2) + lg)) & 15) << 4));

    // --- B: lane's fragment pointer (colfrags wid*2, wid*2+1)
    const unsigned char* wb = wst + (size_t)(wid * 2) * 1024 + (size_t)lane * 16;

    f32x4 acc0[2][2], acc1[2][2], accL[2][2], cmpL[2][2];
#pragma unroll
    for (int i = 0; i < 2; ++i)
#pragma unroll
        for (int j = 0; j < 2; ++j) {
            acc0[i][j] = f32x4{0.f,0.f,0.f,0.f};
            acc1[i][j] = f32x4{0.f,0.f,0.f,0.f};
            accL[i][j] = f32x4{0.f,0.f,0.f,0.f};
            cmpL[i][j] = f32x4{0.f,0.f,0.f,0.f};
        }

    half8 breg[2][2][2];   // [parity kt&1][colfrag][limb]

    auto LOADB = [&](int pp, int kt) {
        const unsigned char* p = wb + (size_t)kt * kWsTileB;
#pragma unroll
        for (int j = 0; j < 2; ++j) {
            breg[pp][j][0] = *reinterpret_cast<const half8*>(p + j * 1024);
            breg[pp][j][1] = *reinterpret_cast<const half8*>(p + j * 1024 + 16384);
        }
    };
    // convert 8 staged floats -> 2 limb vectors, write into buffer at base
    auto WRITESTEP = [&](unsigned base, const float4& a, const float4& b) {
        float v[8];
        *reinterpret_cast<float4*>(v)     = a;
        *reinterpret_cast<float4*>(v + 4) = b;
        half8 h0, h1;
#pragma unroll
        for (int j = 0; j < 8; ++j) {
            const _Float16 hh = (_Float16)v[j];
            h0[j] = hh;
            h1[j] = (_Float16)((v[j] - (float)hh) * kS);
        }
        *reinterpret_cast<half8*>(&lds[base + waddr])        = h0;
        *reinterpret_cast<half8*>(&lds[base + waddr + 2048]) = h1;
    };

    // ---- prologue: stage step 0 into buf0; B tile 0 into breg[0]
    {
        float4 a = *reinterpret_cast<const float4*>(xsrc);
        float4 b = *reinterpret_cast<const float4*>(xsrc + 4);
        LOADB(0, 0);
        WRITESTEP(0, a, b);
    }
    __syncthreads();

    for (int s = 0; s < NSTEP; ++s) {
        const unsigned bufc = (unsigned)((s & 1) << 14);
        const unsigned bufn = (unsigned)(((s + 1) & 1) << 14);
        const bool pre = (s + 1 < NSTEP);
        float4 nv0{0,0,0,0}, nv1{0,0,0,0};
        if (pre) {   // x prefetch for next step: consumed ~4 tiles later
            const float* p = xsrc + (s + 1) * KSTEP;
            nv0 = *reinterpret_cast<const float4*>(p);
            nv1 = *reinterpret_cast<const float4*>(p + 4);
        }

#pragma unroll
        for (int kk = 0; kk < 4; ++kk) {
            const int kt = s * 4 + kk;
            if (kt + 1 < NT) LOADB((kk + 1) & 1, kt + 1);   // next B tile in flight
            // ---- compute tile kk from bufc
            half8 xh[2], xm[2];
#pragma unroll
            for (int i = 0; i < 2; ++i) {
                xh[i] = *reinterpret_cast<const half8*>(&lds[bufc + roff[kk] + i * 1024]);
                xm[i] = *reinterpret_cast<const half8*>(&lds[bufc + roff[kk] + i * 1024 + 2048]);
            }
#pragma unroll
            for (int i = 0; i < 2; ++i)
#pragma unroll
                for (int j = 0; j < 2; ++j)
                    acc0[i][j] = __builtin_amdgcn_mfma_f32_16x16x32_f16(xh[i], breg[kk & 1][j][0], acc0[i][j], 0, 0, 0);
#pragma unroll
            for (int i = 0; i < 2; ++i)
#pragma unroll
                for (int j = 0; j < 2; ++j)
                    acc1[i][j] = __builtin_amdgcn_mfma_f32_16x16x32_f16(xm[i], breg[kk & 1][j][0], acc1[i][j], 0, 0, 0);
#pragma unroll
            for (int i = 0; i < 2; ++i)
#pragma unroll
                for (int j = 0; j < 2; ++j)
                    acc1[i][j] = __builtin_amdgcn_mfma_f32_16x16x32_f16(xh[i], breg[kk & 1][j][1], acc1[i][j], 0, 0, 0);
        }

        if (pre) WRITESTEP(bufn, nv0, nv1);

        if (((s + 1) & 3) == 0) {   // Kahan spill of acc0 every 16 tiles
#pragma unroll
            for (int i = 0; i < 2; ++i)
#pragma unroll
                for (int j = 0; j < 2; ++j) {
                    f32x4 y = acc0[i][j] - cmpL[i][j];
                    f32x4 ss = accL[i][j] + y;
                    cmpL[i][j] = (ss - accL[i][j]) - y;
                    accL[i][j] = ss;
                    acc0[i][j] = f32x4{0.f,0.f,0.f,0.f};
                }
        }
        __syncthreads();
    }

    // ---- epilogue: combine limb levels, biased scores -> LDS
    float (*sc)[257] = reinterpret_cast<float (*)[257]>(lds);   // 32896 B, aliases A bufs
#pragma unroll
    for (int j = 0; j < 2; ++j) {
        const int col  = wid * 32 + j * 16 + l15;
        const float bv = bias[col];
#pragma unroll
        for (int i = 0; i < 2; ++i) {
            f32x4 z = (accL[i][j] + acc0[i][j]) + kC * acc1[i][j];
#pragma unroll
            for (int r = 0; r < 4; ++r) {
                const int row = i * 16 + lg * 4 + r;
                const float s = 1.0f / (1.0f + expf(-z[r]));
                sc[row][col] = s + bv;
            }
        }
    }
    __syncthreads();

    // ---- top-8 per row: 16 lanes/row, iterative argmax, ties -> lowest index
    const int rr = t >> 4;
    const int g  = t & 15;

    float cval[kTopK];
    int   cidx[kTopK];

#pragma unroll
    for (int r = 0; r < kTopK; ++r) {
        float best = -INFINITY;
        int   bi   = kE;
        const float* rowp = sc[rr] + g * 16;
#pragma unroll 8
        for (int c = 0; c < 16; ++c) {
            const float v  = rowp[c];
            const int   ci = g * 16 + c;
            if (v > best || (v == best && ci < bi)) { best = v; bi = ci; }
        }
#pragma unroll
        for (int off = 8; off > 0; off >>= 1) {
            const float ov = __shfl_xor(best, off, 16);
            const int   oi = __shfl_xor(bi,   off, 16);
            if (ov > best || (ov == best && oi < bi)) { best = ov; bi = oi; }
        }
        cval[r] = best;
        cidx[r] = bi;
        if ((bi >> 4) == g) sc[rr][bi] = -INFINITY;   // owner lane retires winner
        __syncthreads();
    }

    if (g == 0) {
        float uw[kTopK];
        float wsum = 0.0f;
#pragma unroll
        for (int r = 0; r < kTopK; ++r) {
            uw[r] = cval[r] - bias[cidx[r]];   // recover unbiased sigmoid score
            wsum += uw[r];
        }
        const float scale = kRouteScale / wsum;
        const size_t grow = (size_t)(m0 + rr);
#pragma unroll
        for (int r = 0; r < kTopK; ++r)
            out[grow * kTopK + r] = uw[r] * scale;
#pragma unroll
        for (int r = 0; r < kTopK; ++r)
            out[(size_t)kTokens * kTopK + grow * kTopK + r] = (float)cidx[r];
    }
}

// ---------------------------------------------------------------------------
// Fallback (round-1 fp32 kernel, known-good) if ws is too small.
// ---------------------------------------------------------------------------
constexpr int FBM = 32;
constexpr int FBK = 32;
constexpr int XS_STRIDE = 36;
constexpr int SC_STRIDE = 260;

__global__ __launch_bounds__(256, 2)
void gate_fused(const float* __restrict__ x,
                const float* __restrict__ W,
                const float* __restrict__ bias,
                float* __restrict__ out)
{
    __shared__ float smem[FBK * XS_STRIDE + FBK * kE];
    float (*xs)[XS_STRIDE] = reinterpret_cast<float (*)[XS_STRIDE]>(smem);
    float (*ws)[kE]        = reinterpret_cast<float (*)[kE]>(smem + FBK * XS_STRIDE);
    float (*sc)[SC_STRIDE] = reinterpret_cast<float (*)[SC_STRIDE]>(smem);

    const int t  = threadIdx.x;
    const int tx = t & 31;
    const int ty = t >> 5;
    const int m0 = blockIdx.x * FBM;
    const int lm = t >> 3;
    const int lc = t & 7;

    float acc[4][8];
    float cmp[4][8];
#pragma unroll
    for (int i = 0; i < 4; ++i)
#pragma unroll
        for (int j = 0; j < 8; ++j) { acc[i][j] = 0.0f; cmp[i][j] = 0.0f; }

    const float* xrow = x + (size_t)(m0 + lm) * kD;
    const float* wrow = W + (size_t)t * kD;

    for (int k0 = 0; k0 < kD; k0 += FBK) {
        float4 xv = *reinterpret_cast<const float4*>(xrow + k0 + 4 * lc);
        float4 wv[8];
#pragma unroll
        for (int i = 0; i < 8; ++i)
            wv[i] = *reinterpret_cast<const float4*>(wrow + k0 + 4 * i);
        __syncthreads();
        xs[4 * lc + 0][lm] = xv.x; xs[4 * lc + 1][lm] = xv.y;
        xs[4 * lc + 2][lm] = xv.z; xs[4 * lc + 3][lm] = xv.w;
#pragma unroll
        for (int i = 0; i < 8; ++i) {
            ws[4 * i + 0][t] = wv[i].x; ws[4 * i + 1][t] = wv[i].y;
            ws[4 * i + 2][t] = wv[i].z; ws[4 * i + 3][t] = wv[i].w;
        }
        __syncthreads();
        float p[4][8];
#pragma unroll
        for (int i = 0; i < 4; ++i)
#pragma unroll
            for (int j = 0; j < 8; ++j) p[i][j] = 0.0f;
#pragma unroll
        for (int k = 0; k < FBK; ++k) {
            float a[4], b[8];
            *reinterpret_cast<float4*>(a)     = *reinterpret_cast<const float4*>(&xs[k][4 * ty]);
            *reinterpret_cast<float4*>(b)     = *reinterpret_cast<const float4*>(&ws[k][4 * tx]);
            *reinterpret_cast<float4*>(b + 4) = *reinterpret_cast<const float4*>(&ws[k][128 + 4 * tx]);
#pragma unroll
            for (int i = 0; i < 4; ++i)
#pragma unroll
                for (int j = 0; j < 8; ++j)
                    p[i][j] = fmaf(a[i], b[j], p[i][j]);
        }
#pragma unroll
        for (int i = 0; i < 4; ++i)
#pragma unroll
            for (int j = 0; j < 8; ++j) {
                const float y = p[i][j] - cmp[i][j];
                const float s = acc[i][j] + y;
                cmp[i][j] = (s - acc[i][j]) - y;
                acc[i][j] = s;
            }
    }
    __syncthreads();
#pragma unroll
    for (int i = 0; i < 4; ++i) {
        const int row = 4 * ty + i;
#pragma unroll
        for (int j = 0; j < 8; ++j) {
            const int col = (j < 4) ? (4 * tx + j) : (128 + 4 * tx + (j - 4));
            const float s = 1.0f / (1.0f + expf(-acc[i][j]));
            sc[row][col] = s + bias[col];
        }
    }
    __syncthreads();
    const int rr = t >> 3;
    const int g  = t & 7;
    float cval[kTopK];
    int   cidx[kTopK];
#pragma unroll
    for (int r = 0; r < kTopK; ++r) {
        float best = -INFINITY;
        int   bi   = kE;
        const float* rowp = sc[rr] + g * 32;
#pragma unroll 8
        for (int c = 0; c < 32; ++c) {
            const float v  = rowp[c];
            const int   ci = g * 32 + c;
            if (v > best || (v == best && ci < bi)) { best = v; bi = ci; }
        }
#pragma unroll
        for (int off = 4; off > 0; off >>= 1) {
            const float ov = __shfl_xor(best, off, 8);
            const int   oi = __shfl_xor(bi,   off, 8);
            if (ov > best || (ov == best && oi < bi)) { best = ov; bi = oi; }
        }
        cval[r] = best; cidx[r] = bi;
        if ((bi >> 5) == g) sc[rr][bi] = -INFINITY;
        __syncthreads();
    }
    if (g == 0) {
        float uw[kTopK];
        float wsum = 0.0f;
#pragma unroll
        for (int r = 0; r < kTopK; ++r) { uw[r] = cval[r] - bias[cidx[r]]; wsum += uw[r]; }
        const float scale = kRouteScale / wsum;
        const size_t grow = (size_t)(m0 + rr);
#pragma unroll
        for (int r = 0; r < kTopK; ++r) out[grow * kTopK + r] = uw[r] * scale;
#pragma unroll
        for (int r = 0; r < kTopK; ++r)
            out[(size_t)kTokens * kTopK + grow * kTopK + r] = (float)cidx[r];
    }
}

} // namespace

extern "C" void kernel_launch(void* const* d_in, const int* in_sizes, int n_in,
                              void* d_out, int out_size, void* d_ws, size_t ws_size,
                              hipStream_t stream)
{
    const float* x    = (const float*)d_in[0];
    const float* W    = (const float*)d_in[1];
    const float* bias = (const float*)d_in[2];
    float* out = (float*)d_out;

    if (ws_size >= kWsNeed) {
        unsigned char* ws = (unsigned char*)d_ws;
        hipLaunchKernelGGL(wconv_kernel, dim3(kE), dim3(kD / 8), 0, stream, W, ws);
        hipLaunchKernelGGL(gate_mfma, dim3(kTokens / BM), dim3(512), 0, stream, x, ws, bias, out);
    } else {
        hipLaunchKernelGGL(gate_fused, dim3(kTokens / FBM), dim3(256), 0, stream, x, W, bias, out);
    }
}

// Round 7
// 256.646 us; speedup vs baseline: 1.9986x; 1.0118x over previous
//
#include <hip/hip_runtime.h>
#include <cmath>

namespace {

typedef _Float16 half8 __attribute__((ext_vector_type(8)));
typedef float f32x4 __attribute__((ext_vector_type(4)));

constexpr int kTokens = 16384;
constexpr int kD      = 7168;
constexpr int kE      = 256;
constexpr int kTopK   = 8;
constexpr float kRouteScale = 2.5f;

constexpr int BM     = 32;
constexpr int BK     = 32;               // MFMA k-tile
constexpr int KSTEP  = 128;              // k per barrier step (4 tiles)
constexpr int NT     = kD / BK;          // 224 k-tiles
constexpr int NSTEP  = kD / KSTEP;       // 56 steps
constexpr float kS  = 4096.0f;           // limb scale 2^12
constexpr float kC  = 0.000244140625f;   // 2^-12 (exact)
constexpr size_t kWsTileB = 32768;       // per-ktile W image: limb0 16K + limb1 16K
constexpr size_t kWsNeed  = (size_t)NT * kWsTileB;   // 7,340,032 B

// ---------------------------------------------------------------------------
// Pre-pass: W [256][7168] f32 -> per-ktile B-fragment images, 2 scaled f16
// limbs.  Slot for expert e, k-group kg (8 k's): (e>>4)*64 + kg*16 + (e&15).
// Lane l of a wave reading colfrag f at f*1024 + l*16 gets its MFMA B frag.
// ---------------------------------------------------------------------------
__global__ void wconv_kernel(const float* __restrict__ W, unsigned char* __restrict__ ws)
{
    const int e = blockIdx.x;
    const int t = threadIdx.x;            // 0..895
    const float* src = W + (size_t)e * kD + (size_t)t * 8;
    float v[8];
    *reinterpret_cast<float4*>(v)     = *reinterpret_cast<const float4*>(src);
    *reinterpret_cast<float4*>(v + 4) = *reinterpret_cast<const float4*>(src + 4);
    half8 h, l;
#pragma unroll
    for (int j = 0; j < 8; ++j) {
        _Float16 hh = (_Float16)v[j];
        h[j] = hh;
        l[j] = (_Float16)((v[j] - (float)hh) * kS);
    }
    const int kt = t >> 2;
    const int kg = t & 3;
    const size_t off = (size_t)kt * kWsTileB +
                       (size_t)(((e >> 4) << 6) + (kg << 4) + (e & 15)) * 16;
    *reinterpret_cast<half8*>(ws + off)         = h;
    *reinterpret_cast<half8*>(ws + off + 16384) = l;
}

// ---------------------------------------------------------------------------
// Main fused kernel.  512 threads = 8 waves; block tile 32x256; wave tile
// 32x32.  Barrier step = 128 k (4 MFMA sub-tiles).  Anti-serialization
// structure (round-7): A-fragment REGISTER DOUBLE BUFFER — the ds_reads for
// sub-tile kk+1 are issued BEFORE the MFMA cluster of kk, so the LDS pipe
// serves kk+1 while the matrix pipe runs kk.  B: wh double-buffered
// global->reg one sub-tile ahead; wl single-buffered, issued at sub-tile top
// and consumed by the last 4 MFMAs (~8 MFMA slots of cover > L2 latency).
// Numerics: 3 products (xh*wh -> acc0; xm*wh + xh*wl -> acc1), acc0 spilled
// into accL every 8 steps (plain two-level; est logit RMS ~1.9e-7).
// Grid 512 = 2 blocks/CU; total regs budgeted <= 128 for 4 waves/SIMD.
// LDS: A bufs 2x16KB (limbs, XOR slot swizzle), aliased by epilogue sc.
// ---------------------------------------------------------------------------
__global__ __launch_bounds__(512, 4)
void gate_mfma(const float* __restrict__ x,
               const unsigned char* __restrict__ wst,
               const float* __restrict__ bias,
               float* __restrict__ out)
{
    __shared__ unsigned char lds[32896];

    const int t    = threadIdx.x;
    const int lane = t & 63;
    const int wid  = t >> 6;             // 0..7 -> 32-col group
    const int m0   = blockIdx.x * BM;
    const int l15  = lane & 15;
    const int lg   = lane >> 4;

    // --- A staging map: thread t stages 8 consecutive k's of one row.
    const int srow = t >> 4;             // 0..31
    const int skc  = t & 15;             // k chunk: k = skc*8 .. +7 (within step)
    const unsigned waddr = (unsigned)(((skc >> 2) << 12) + ((srow >> 4) << 10) +
                                      ((skc & 3) << 8) + ((((srow & 15) ^ skc) & 15) << 4));
    const float* xsrc = x + (size_t)(m0 + srow) * kD + (size_t)(skc * 8);

    // --- B: lane's fragment pointer (colfrags wid*2, wid*2+1)
    const unsigned char* wb = wst + (size_t)(wid * 2) * 1024 + (size_t)lane * 16;

    f32x4 acc0[2][2], acc1[2][2], accL[2][2];
#pragma unroll
    for (int i = 0; i < 2; ++i)
#pragma unroll
        for (int j = 0; j < 2; ++j) {
            acc0[i][j] = f32x4{0.f,0.f,0.f,0.f};
            acc1[i][j] = f32x4{0.f,0.f,0.f,0.f};
            accL[i][j] = f32x4{0.f,0.f,0.f,0.f};
        }

    half8 bh[2][2];      // [parity][colfrag]  W limb0, 1 sub-tile ahead
    half8 bl[2];         // [colfrag]          W limb1, current sub-tile (JIT)
    half8 axh[2][2];     // [parity][rowfrag]  A limb0
    half8 axm[2][2];     // [parity][rowfrag]  A limb1

    auto LOADBH = [&](int pp, int kt) {
        const unsigned char* p = wb + (size_t)kt * kWsTileB;
        bh[pp][0] = *reinterpret_cast<const half8*>(p);
        bh[pp][1] = *reinterpret_cast<const half8*>(p + 1024);
    };
    auto LOADBL = [&](int kt) {
        const unsigned char* p = wb + (size_t)kt * kWsTileB + 16384;
        bl[0] = *reinterpret_cast<const half8*>(p);
        bl[1] = *reinterpret_cast<const half8*>(p + 1024);
    };
    auto LDA = [&](int pp, unsigned bufc, int kk) {
        const unsigned base = bufc + (unsigned)(kk << 12) + (unsigned)(lg << 8) +
                              (unsigned)((((l15 ^ ((kk << 2) + lg)) & 15) << 4));
        axh[pp][0] = *reinterpret_cast<const half8*>(&lds[base]);
        axh[pp][1] = *reinterpret_cast<const half8*>(&lds[base + 1024]);
        axm[pp][0] = *reinterpret_cast<const half8*>(&lds[base + 2048]);
        axm[pp][1] = *reinterpret_cast<const half8*>(&lds[base + 3072]);
    };
    // convert 8 staged floats -> 2 limb vectors, write into buffer at base
    auto WRITESTEP = [&](unsigned base, const float4& a, const float4& b) {
        float v[8];
        *reinterpret_cast<float4*>(v)     = a;
        *reinterpret_cast<float4*>(v + 4) = b;
        half8 h0, h1;
#pragma unroll
        for (int j = 0; j < 8; ++j) {
            const _Float16 hh = (_Float16)v[j];
            h0[j] = hh;
            h1[j] = (_Float16)((v[j] - (float)hh) * kS);
        }
        *reinterpret_cast<half8*>(&lds[base + waddr])        = h0;
        *reinterpret_cast<half8*>(&lds[base + waddr + 2048]) = h1;
    };

    // ---- prologue: stage step 0 into buf0; wh tile 0 into parity 0
    {
        float4 a = *reinterpret_cast<const float4*>(xsrc);
        float4 b = *reinterpret_cast<const float4*>(xsrc + 4);
        LOADBH(0, 0);
        WRITESTEP(0, a, b);
    }
    __syncthreads();

    for (int s = 0; s < NSTEP; ++s) {
        const unsigned bufc = (unsigned)((s & 1) << 14);
        const unsigned bufn = (unsigned)(((s + 1) & 1) << 14);
        const bool pre = (s + 1 < NSTEP);

        LDA(0, bufc, 0);                 // sub-tile 0 A-frags
        float4 nv0{0,0,0,0}, nv1{0,0,0,0};
        if (pre) {                       // x prefetch for next step (HBM, used at step end)
            const float* p = xsrc + (s + 1) * KSTEP;
            nv0 = *reinterpret_cast<const float4*>(p);
            nv1 = *reinterpret_cast<const float4*>(p + 4);
        }

#pragma unroll
        for (int kk = 0; kk < 4; ++kk) {
            const int kt = s * 4 + kk;
            LOADBL(kt);                                  // wl for THIS sub-tile (used last)
            if (kk < 3) LDA((kk + 1) & 1, bufc, kk + 1); // next A frags in flight over MFMAs
            if (kt + 1 < NT) LOADBH((kk + 1) & 1, kt + 1);
            const int pp = kk & 1;
            // ---- 12-MFMA cluster (LDS/VMEM for kk+1 already in flight above)
#pragma unroll
            for (int i = 0; i < 2; ++i)
#pragma unroll
                for (int j = 0; j < 2; ++j)
                    acc0[i][j] = __builtin_amdgcn_mfma_f32_16x16x32_f16(axh[pp][i], bh[pp][j], acc0[i][j], 0, 0, 0);
#pragma unroll
            for (int i = 0; i < 2; ++i)
#pragma unroll
                for (int j = 0; j < 2; ++j)
                    acc1[i][j] = __builtin_amdgcn_mfma_f32_16x16x32_f16(axm[pp][i], bh[pp][j], acc1[i][j], 0, 0, 0);
#pragma unroll
            for (int i = 0; i < 2; ++i)
#pragma unroll
                for (int j = 0; j < 2; ++j)
                    acc1[i][j] = __builtin_amdgcn_mfma_f32_16x16x32_f16(axh[pp][i], bl[j], acc1[i][j], 0, 0, 0);
        }

        if (pre) WRITESTEP(bufn, nv0, nv1);

        if (((s + 1) & 7) == 0) {        // two-level spill of acc0 every 8 steps
#pragma unroll
            for (int i = 0; i < 2; ++i)
#pragma unroll
                for (int j = 0; j < 2; ++j) {
                    accL[i][j] += acc0[i][j];
                    acc0[i][j] = f32x4{0.f,0.f,0.f,0.f};
                }
        }
        __syncthreads();
    }

    // ---- epilogue: combine limb levels, biased scores -> LDS
    float (*sc)[257] = reinterpret_cast<float (*)[257]>(lds);   // 32896 B, aliases A bufs
#pragma unroll
    for (int j = 0; j < 2; ++j) {
        const int col  = wid * 32 + j * 16 + l15;
        const float bv = bias[col];
#pragma unroll
        for (int i = 0; i < 2; ++i) {
            f32x4 z = (accL[i][j] + acc0[i][j]) + kC * acc1[i][j];
#pragma unroll
            for (int r = 0; r < 4; ++r) {
                const int row = i * 16 + lg * 4 + r;
                const float s = 1.0f / (1.0f + expf(-z[r]));
                sc[row][col] = s + bv;
            }
        }
    }
    __syncthreads();

    // ---- top-8 per row: 16 lanes/row (one 16-group of a wave -> no barriers
    // needed between rounds; LDS ops are wave-ordered), ties -> lowest index
    const int rr = t >> 4;
    const int g  = t & 15;

    float cval[kTopK];
    int   cidx[kTopK];

#pragma unroll
    for (int r = 0; r < kTopK; ++r) {
        float best = -INFINITY;
        int   bi   = kE;
        const float* rowp = sc[rr] + g * 16;
#pragma unroll 8
        for (int c = 0; c < 16; ++c) {
            const float v  = rowp[c];
            const int   ci = g * 16 + c;
            if (v > best || (v == best && ci < bi)) { best = v; bi = ci; }
        }
#pragma unroll
        for (int off = 8; off > 0; off >>= 1) {
            const float ov = __shfl_xor(best, off, 16);
            const int   oi = __shfl_xor(bi,   off, 16);
            if (ov > best || (ov == best && oi < bi)) { best = ov; bi = oi; }
        }
        cval[r] = best;
        cidx[r] = bi;
        if ((bi >> 4) == g) sc[rr][bi] = -INFINITY;   // owner lane retires winner
    }

    if (g == 0) {
        float uw[kTopK];
        float wsum = 0.0f;
#pragma unroll
        for (int r = 0; r < kTopK; ++r) {
            uw[r] = cval[r] - bias[cidx[r]];   // recover unbiased sigmoid score
            wsum += uw[r];
        }
        const float scale = kRouteScale / wsum;
        const size_t grow = (size_t)(m0 + rr);
#pragma unroll
        for (int r = 0; r < kTopK; ++r)
            out[grow * kTopK + r] = uw[r] * scale;
#pragma unroll
        for (int r = 0; r < kTopK; ++r)
            out[(size_t)kTokens * kTopK + grow * kTopK + r] = (float)cidx[r];
    }
}

// ---------------------------------------------------------------------------
// Fallback (round-1 fp32 kernel, known-good) if ws is too small.
// ---------------------------------------------------------------------------
constexpr int FBM = 32;
constexpr int FBK = 32;
constexpr int XS_STRIDE = 36;
constexpr int SC_STRIDE = 260;

__global__ __launch_bounds__(256, 2)
void gate_fused(const float* __restrict__ x,
                const float* __restrict__ W,
                const float* __restrict__ bias,
                float* __restrict__ out)
{
    __shared__ float smem[FBK * XS_STRIDE + FBK * kE];
    float (*xs)[XS_STRIDE] = reinterpret_cast<float (*)[XS_STRIDE]>(smem);
    float (*ws)[kE]        = reinterpret_cast<float (*)[kE]>(smem + FBK * XS_STRIDE);
    float (*sc)[SC_STRIDE] = reinterpret_cast<float (*)[SC_STRIDE]>(smem);

    const int t  = threadIdx.x;
    const int tx = t & 31;
    const int ty = t >> 5;
    const int m0 = blockIdx.x * FBM;
    const int lm = t >> 3;
    const int lc = t & 7;

    float acc[4][8];
    float cmp[4][8];
#pragma unroll
    for (int i = 0; i < 4; ++i)
#pragma unroll
        for (int j = 0; j < 8; ++j) { acc[i][j] = 0.0f; cmp[i][j] = 0.0f; }

    const float* xrow = x + (size_t)(m0 + lm) * kD;
    const float* wrow = W + (size_t)t * kD;

    for (int k0 = 0; k0 < kD; k0 += FBK) {
        float4 xv = *reinterpret_cast<const float4*>(xrow + k0 + 4 * lc);
        float4 wv[8];
#pragma unroll
        for (int i = 0; i < 8; ++i)
            wv[i] = *reinterpret_cast<const float4*>(wrow + k0 + 4 * i);
        __syncthreads();
        xs[4 * lc + 0][lm] = xv.x; xs[4 * lc + 1][lm] = xv.y;
        xs[4 * lc + 2][lm] = xv.z; xs[4 * lc + 3][lm] = xv.w;
#pragma unroll
        for (int i = 0; i < 8; ++i) {
            ws[4 * i + 0][t] = wv[i].x; ws[4 * i + 1][t] = wv[i].y;
            ws[4 * i + 2][t] = wv[i].z; ws[4 * i + 3][t] = wv[i].w;
        }
        __syncthreads();
        float p[4][8];
#pragma unroll
        for (int i = 0; i < 4; ++i)
#pragma unroll
            for (int j = 0; j < 8; ++j) p[i][j] = 0.0f;
#pragma unroll
        for (int k = 0; k < FBK; ++k) {
            float a[4], b[8];
            *reinterpret_cast<float4*>(a)     = *reinterpret_cast<const float4*>(&xs[k][4 * ty]);
            *reinterpret_cast<float4*>(b)     = *reinterpret_cast<const float4*>(&ws[k][4 * tx]);
            *reinterpret_cast<float4*>(b + 4) = *reinterpret_cast<const float4*>(&ws[k][128 + 4 * tx]);
#pragma unroll
            for (int i = 0; i < 4; ++i)
#pragma unroll
                for (int j = 0; j < 8; ++j)
                    p[i][j] = fmaf(a[i], b[j], p[i][j]);
        }
#pragma unroll
        for (int i = 0; i < 4; ++i)
#pragma unroll
            for (int j = 0; j < 8; ++j) {
                const float y = p[i][j] - cmp[i][j];
                const float s = acc[i][j] + y;
                cmp[i][j] = (s - acc[i][j]) - y;
                acc[i][j] = s;
            }
    }
    __syncthreads();
#pragma unroll
    for (int i = 0; i < 4; ++i) {
        const int row = 4 * ty + i;
#pragma unroll
        for (int j = 0; j < 8; ++j) {
            const int col = (j < 4) ? (4 * tx + j) : (128 + 4 * tx + (j - 4));
            const float s = 1.0f / (1.0f + expf(-acc[i][j]));
            sc[row][col] = s + bias[col];
        }
    }
    __syncthreads();
    const int rr = t >> 3;
    const int g  = t & 7;
    float cval[kTopK];
    int   cidx[kTopK];
#pragma unroll
    for (int r = 0; r < kTopK; ++r) {
        float best = -INFINITY;
        int   bi   = kE;
        const float* rowp = sc[rr] + g * 32;
#pragma unroll 8
        for (int c = 0; c < 32; ++c) {
            const float v  = rowp[c];
            const int   ci = g * 32 + c;
            if (v > best || (v == best && ci < bi)) { best = v; bi = ci; }
        }
#pragma unroll
        for (int off = 4; off > 0; off >>= 1) {
            const float ov = __shfl_xor(best, off, 8);
            const int   oi = __shfl_xor(bi,   off, 8);
            if (ov > best || (ov == best && oi < bi)) { best = ov; bi = oi; }
        }
        cval[r] = best; cidx[r] = bi;
        if ((bi >> 5) == g) sc[rr][bi] = -INFINITY;
        __syncthreads();
    }
    if (g == 0) {
        float uw[kTopK];
        float wsum = 0.0f;
#pragma unroll
        for (int r = 0; r < kTopK; ++r) { uw[r] = cval[r] - bias[cidx[r]]; wsum += uw[r]; }
        const float scale = kRouteScale / wsum;
        const size_t grow = (size_t)(m0 + rr);
#pragma unroll
        for (int r = 0; r < kTopK; ++r) out[grow * kTopK + r] = uw[r] * scale;
#pragma unroll
        for (int r = 0; r < kTopK; ++r)
            out[(size_t)kTokens * kTopK + grow * kTopK + r] = (float)cidx[r];
    }
}

} // namespace

extern "C" void kernel_launch(void* const* d_in, const int* in_sizes, int n_in,
                              void* d_out, int out_size, void* d_ws, size_t ws_size,
                              hipStream_t stream)
{
    const float* x    = (const float*)d_in[0];
    const float* W    = (const float*)d_in[1];
    const float* bias = (const float*)d_in[2];
    float* out = (float*)d_out;

    if (ws_size >= kWsNeed) {
        unsigned char* ws = (unsigned char*)d_ws;
        hipLaunchKernelGGL(wconv_kernel, dim3(kE), dim3(kD / 8), 0, stream, W, ws);
        hipLaunchKernelGGL(gate_mfma, dim3(kTokens / BM), dim3(512), 0, stream, x, ws, bias, out);
    } else {
        hipLaunchKernelGGL(gate_fused, dim3(kTokens / FBM), dim3(256), 0, stream, x, W, bias, out);
    }
}